// Round 4
// baseline (178.564 us; speedup 1.0000x reference)
//
#include <hip/hip_runtime.h>
#include <hip/hip_cooperative_groups.h>

namespace cg = cooperative_groups;

// PoolObj: ball-query (annulus) neighbor-count downsampling + gather.
// B=4, N=4096, D=64, K=2048. Out = concat(new_xyz [B,K,3], new_points [B,K,D]).
//
// Single cooperative kernel, 512 blocks x 256 threads (2 blocks/CU co-resident):
//   phase 1: partial annulus counts, j-split across 32 chunks (disjoint writes)
//   phase 2: sum partials -> key = cnt<<12 | (4095-i)
//            (one int compare == lax.top_k (count desc, index asc) order)
//   phase 3: rank_i = #{j : key_j > key_i}; rank<K -> write xyz + 64 features.
// grid.sync() between phases (device-scope fence included).

#define BN 4
#define NPTS 4096
#define ND 64
#define KSEL 2048
#define R2 0.0025f   // RADIUS^2
#define M2 0.0004f   // MIN_RADIUS^2

#define IPT 4         // i-points per thread (phase 1)
#define ITILES 4      // NPTS / (256*IPT)
#define JC 32         // j-chunks
#define JCH 128       // NPTS / JC
#define GRID (BN * ITILES * JC)   // 512

__global__ __launch_bounds__(256, 2) void pool_fused_kernel(
        const float* __restrict__ xyz, const float* __restrict__ points,
        int* __restrict__ part, int* __restrict__ key,
        float* __restrict__ out) {
    cg::grid_group grid = cg::this_grid();

    __shared__ alignas(16) int skey[NPTS];   // 16 KB (phase 1 aliases as float4)
    __shared__ int spr[8][32];
    __shared__ int srank[32];

    const int blk = blockIdx.x;
    const int tid = threadIdx.x;

    // ---------- phase 1: partial counts ----------
    {
        float4* sj = (float4*)skey;          // 128 * 16 B = 2 KB of skey
        const int jc = blk & (JC - 1);
        const int it = (blk >> 5) & (ITILES - 1);
        const int b  = blk >> 7;
        const float* base = xyz + (size_t)b * 3 * NPTS;

        if (tid < JCH) {
            int j = jc * JCH + tid;
            float x = base[j], y = base[NPTS + j], z = base[2 * NPTS + j];
            // sq = (x*x + y*y) + z*z, no FMA contraction (bit-match numpy)
            float sq = __fadd_rn(__fadd_rn(__fmul_rn(x, x), __fmul_rn(y, y)),
                                 __fmul_rn(z, z));
            sj[tid] = make_float4(x, y, z, sq);
        }
        const int ibase = it * 1024 + tid;
        float4 mi[IPT];
        #pragma unroll
        for (int k = 0; k < IPT; ++k) {
            int i = ibase + k * 256;
            float x = base[i], y = base[NPTS + i], z = base[2 * NPTS + i];
            float sq = __fadd_rn(__fadd_rn(__fmul_rn(x, x), __fmul_rn(y, y)),
                                 __fmul_rn(z, z));
            mi[k] = make_float4(x, y, z, sq);
        }
        __syncthreads();

        int cnt[IPT] = {0, 0, 0, 0};
        #pragma unroll 4
        for (int j = 0; j < JCH; ++j) {
            float4 p = sj[j];
            #pragma unroll
            for (int k = 0; k < IPT; ++k) {
                float dot = __fadd_rn(__fadd_rn(__fmul_rn(mi[k].x, p.x),
                                                __fmul_rn(mi[k].y, p.y)),
                                      __fmul_rn(mi[k].z, p.z));
                float d2 = __fsub_rn(__fadd_rn(mi[k].w, p.w),
                                     __fmul_rn(2.0f, dot));
                cnt[k] += (d2 < R2 && d2 > M2) ? 1 : 0;
            }
        }
        int* pp = part + (size_t)((b * ITILES + it) * JC + jc) * 1024;
        #pragma unroll
        for (int k = 0; k < IPT; ++k) pp[tid + k * 256] = cnt[k];
    }

    grid.sync();

    // ---------- phase 2: sum partials -> packed key ----------
    {
        const int p    = blk * 32 + (tid >> 3);   // global point id
        const int tid8 = tid & 7;                 // 8 threads per point
        const int b2    = p >> 12;
        const int i2    = p & (NPTS - 1);
        const int it2   = i2 >> 10;
        const int local = i2 & 1023;
        const int* pb = part + (size_t)(b2 * ITILES + it2) * JC * 1024 + local;
        int c = 0;
        #pragma unroll
        for (int u = 0; u < 4; ++u) c += pb[(tid8 * 4 + u) * 1024];
        c += __shfl_down(c, 4, 8);
        c += __shfl_down(c, 2, 8);
        c += __shfl_down(c, 1, 8);
        if (tid8 == 0) key[p] = (c << 12) | (NPTS - 1 - i2);
    }

    grid.sync();

    // ---------- phase 3: rank + gather ----------
    const int b3    = blk >> 7;
    const int tbase = (blk & 127) * 32;
    {
        const int4* kg = (const int4*)(key + (size_t)b3 * NPTS);
        int4* sk4 = (int4*)skey;
        #pragma unroll
        for (int idx = tid; idx < NPTS / 4; idx += 256) sk4[idx] = kg[idx];
    }
    __syncthreads();

    {
        const int pi = tid & 31;
        const int q  = tid >> 5;                 // 8 j-slices per point
        const int ki = skey[tbase + pi];
        const int4* sk4 = (const int4*)skey;
        int r = 0;
        #pragma unroll 4
        for (int jj = q * 128; jj < q * 128 + 128; ++jj) {
            int4 v = sk4[jj];
            r += (v.x > ki) ? 1 : 0;
            r += (v.y > ki) ? 1 : 0;
            r += (v.z > ki) ? 1 : 0;
            r += (v.w > ki) ? 1 : 0;
        }
        spr[q][pi] = r;
    }
    __syncthreads();

    if (tid < 32) {
        int rank = 0;
        #pragma unroll
        for (int q = 0; q < 8; ++q) rank += spr[q][tid];
        srank[tid] = rank;
        const int i = tbase + tid;
        if (rank < KSEL) {
            const float* xb = xyz + (size_t)b3 * 3 * NPTS;
            float* o = out + ((size_t)b3 * KSEL + rank) * 3;
            o[0] = xb[i]; o[1] = xb[NPTS + i]; o[2] = xb[2 * NPTS + i];
        }
    }
    __syncthreads();

    {
        const int pt = tid & 31;                 // lanes 0..31: consecutive pts
        const int cw = tid >> 5;                 // channel group
        const int rank = srank[pt];
        float* ofeat = out + (size_t)BN * KSEL * 3;
        #pragma unroll
        for (int r8 = 0; r8 < 8; ++r8) {
            int c = cw + 8 * r8;
            float v = points[((size_t)b3 * ND + c) * NPTS + tbase + pt];
            if (rank < KSEL) ofeat[((size_t)b3 * KSEL + rank) * ND + c] = v;
        }
    }
}

extern "C" void kernel_launch(void* const* d_in, const int* in_sizes, int n_in,
                              void* d_out, int out_size, void* d_ws, size_t ws_size,
                              hipStream_t stream) {
    const float* xyz    = (const float*)d_in[0];   // [B, 3, N, 1]
    const float* points = (const float*)d_in[1];   // [B, D, N, 1]
    float* out = (float*)d_out;

    char* ws = (char*)d_ws;
    int* part = (int*)ws;                           // 2 MB
    int* key  = (int*)(ws + 2 * 1024 * 1024);       // 64 KB

    void* args[] = {(void*)&xyz, (void*)&points, (void*)&part,
                    (void*)&key, (void*)&out};
    hipLaunchCooperativeKernel((const void*)pool_fused_kernel,
                               dim3(GRID), dim3(256), args, 0, stream);
}

// Round 5
// 90.385 us; speedup vs baseline: 1.9756x; 1.9756x over previous
//
#include <hip/hip_runtime.h>

// PoolObj: ball-query (annulus) neighbor-count downsampling + gather.
// B=4, N=4096, D=64, K=2048. Out = concat(new_xyz [B,K,3], new_points [B,K,D]).
//
// 2 plain kernels (grid.sync measured at ~45us/sync on gfx950 -- round 4 --
// so phases are split at kernel boundaries instead):
//   K1 count_part  : partial annulus counts, j-split (32 chunks), disjoint
//                    writes, no zero-init, no atomics.
//   K2 rank_gather : every block re-sums the 32 partials for all 4096 points
//                    of its batch into LDS keys (redundant but only ~4us of
//                    L2 traffic; cheaper than a separate kernel node), ranks
//                    its 64 owned points, writes xyz + 64 features.
// key = cnt<<12 | (4095-i): one int compare == lax.top_k (count desc, index
// asc) order; ranks are a permutation so each output slot written once.

#define BN 4
#define NPTS 4096
#define ND 64
#define KSEL 2048
#define R2 0.0025f   // RADIUS^2
#define M2 0.0004f   // MIN_RADIUS^2

#define IPT 4         // i-points per thread
#define ITILES 4      // NPTS / (256*IPT)
#define JC 32         // j-chunks
#define JCH 128       // NPTS / JC

// K1: grid = BN*ITILES*JC = 512 blocks.
__global__ __launch_bounds__(256) void count_part_kernel(
        const float* __restrict__ xyz, int* __restrict__ part) {
    __shared__ float4 sj[JCH];   // 2 KB
    const int jc = blockIdx.x & (JC - 1);
    const int it = (blockIdx.x >> 5) & (ITILES - 1);
    const int b  = blockIdx.x >> 7;
    const float* base = xyz + (size_t)b * 3 * NPTS;

    if (threadIdx.x < JCH) {
        int j = jc * JCH + threadIdx.x;
        float x = base[j], y = base[NPTS + j], z = base[2 * NPTS + j];
        // sq = (x*x + y*y) + z*z, no FMA contraction (bit-match numpy)
        float sq = __fadd_rn(__fadd_rn(__fmul_rn(x, x), __fmul_rn(y, y)),
                             __fmul_rn(z, z));
        sj[threadIdx.x] = make_float4(x, y, z, sq);
    }
    const int ibase = it * 1024 + threadIdx.x;
    float4 mi[IPT];
    #pragma unroll
    for (int k = 0; k < IPT; ++k) {
        int i = ibase + k * 256;
        float x = base[i], y = base[NPTS + i], z = base[2 * NPTS + i];
        float sq = __fadd_rn(__fadd_rn(__fmul_rn(x, x), __fmul_rn(y, y)),
                             __fmul_rn(z, z));
        mi[k] = make_float4(x, y, z, sq);
    }
    __syncthreads();

    int cnt[IPT] = {0, 0, 0, 0};
    #pragma unroll 4
    for (int j = 0; j < JCH; ++j) {
        float4 p = sj[j];
        #pragma unroll
        for (int k = 0; k < IPT; ++k) {
            float dot = __fadd_rn(__fadd_rn(__fmul_rn(mi[k].x, p.x),
                                            __fmul_rn(mi[k].y, p.y)),
                                  __fmul_rn(mi[k].z, p.z));
            float d2 = __fsub_rn(__fadd_rn(mi[k].w, p.w), __fmul_rn(2.0f, dot));
            cnt[k] += (d2 < R2 && d2 > M2) ? 1 : 0;
        }
    }
    int* pp = part + (size_t)((b * ITILES + it) * JC + jc) * 1024;
    #pragma unroll
    for (int k = 0; k < IPT; ++k) pp[threadIdx.x + k * 256] = cnt[k];
}

// K2: grid = BN*64 = 256 blocks; block owns 64 consecutive i of batch b.
__global__ __launch_bounds__(256) void rank_gather_kernel(
        const float* __restrict__ xyz, const float* __restrict__ points,
        const int* __restrict__ part, float* __restrict__ out) {
    __shared__ alignas(16) int skey[NPTS];   // 16 KB
    __shared__ int spr[4][64];
    __shared__ int srank[64];
    const int b     = blockIdx.x >> 6;
    const int tbase = (blockIdx.x & 63) * 64;
    const int tid   = threadIdx.x;

    // ---- phase A: sum partials for ALL 4096 points of batch b -> LDS keys
    {
        int4* sk4 = (int4*)skey;
        const int* pbase = part + (size_t)b * ITILES * JC * 1024;
        #pragma unroll
        for (int gg = 0; gg < 4; ++gg) {
            const int g    = tid + gg * 256;      // int4-group of 4 points
            const int it   = g >> 8;
            const int loc4 = (g & 255) * 4;
            const int4* pp =
                (const int4*)(pbase + (size_t)it * JC * 1024 + loc4);
            int4 s = make_int4(0, 0, 0, 0);
            #pragma unroll 8
            for (int jc = 0; jc < JC; ++jc) {     // stride 1024 ints = 256 int4
                int4 v = pp[jc * 256];
                s.x += v.x; s.y += v.y; s.z += v.z; s.w += v.w;
            }
            const int i0 = it * 1024 + loc4;
            int4 kv;
            kv.x = (s.x << 12) | (NPTS - 1 - (i0 + 0));
            kv.y = (s.y << 12) | (NPTS - 1 - (i0 + 1));
            kv.z = (s.z << 12) | (NPTS - 1 - (i0 + 2));
            kv.w = (s.w << 12) | (NPTS - 1 - (i0 + 3));
            sk4[g] = kv;   // i0/4 == g
        }
    }
    __syncthreads();

    // ---- phase B: rank own 64 points (wave-broadcast b128 reads, free)
    {
        const int pi = tid & 63;
        const int q  = tid >> 6;                  // 4 j-slices per point
        const int ki = skey[tbase + pi];
        const int4* sk4 = (const int4*)skey;
        int r = 0;
        #pragma unroll 8
        for (int jj = q * 256; jj < q * 256 + 256; ++jj) {
            int4 v = sk4[jj];
            r += (v.x > ki) ? 1 : 0;
            r += (v.y > ki) ? 1 : 0;
            r += (v.z > ki) ? 1 : 0;
            r += (v.w > ki) ? 1 : 0;
        }
        spr[q][pi] = r;
    }
    __syncthreads();

    if (tid < 64) {
        const int rank = spr[0][tid] + spr[1][tid] + spr[2][tid] + spr[3][tid];
        srank[tid] = rank;
        const int i = tbase + tid;
        if (rank < KSEL) {
            const float* xb = xyz + (size_t)b * 3 * NPTS;
            float* o = out + ((size_t)b * KSEL + rank) * 3;
            o[0] = xb[i]; o[1] = xb[NPTS + i]; o[2] = xb[2 * NPTS + i];
        }
    }
    __syncthreads();

    // ---- phase C: features; wave q covers c = q,q+4,...; lane = point
    {
        const int ii   = tid & 63;
        const int q    = tid >> 6;
        const int rank = srank[ii];
        float* ofeat = out + (size_t)BN * KSEL * 3;
        #pragma unroll
        for (int r16 = 0; r16 < 16; ++r16) {
            const int c = q + 4 * r16;
            float v = points[((size_t)b * ND + c) * NPTS + tbase + ii];
            if (rank < KSEL) ofeat[((size_t)b * KSEL + rank) * ND + c] = v;
        }
    }
}

extern "C" void kernel_launch(void* const* d_in, const int* in_sizes, int n_in,
                              void* d_out, int out_size, void* d_ws, size_t ws_size,
                              hipStream_t stream) {
    const float* xyz    = (const float*)d_in[0];   // [B, 3, N, 1]
    const float* points = (const float*)d_in[1];   // [B, D, N, 1]
    float* out = (float*)d_out;
    int* part = (int*)d_ws;                        // 2 MB partial counts

    count_part_kernel<<<BN * ITILES * JC, 256, 0, stream>>>(xyz, part);
    rank_gather_kernel<<<BN * 64, 256, 0, stream>>>(xyz, points, part, out);
}

// Round 6
// 89.410 us; speedup vs baseline: 1.9971x; 1.0109x over previous
//
#include <hip/hip_runtime.h>

// PoolObj: ball-query (annulus) neighbor-count downsampling + gather.
// B=4, N=4096, D=64, K=2048. Out = concat(new_xyz [B,K,3], new_points [B,K,D]).
//
// Fixed harness overhead (ws 0xAA fill etc.) ~68us; our kernels are the rest.
//   K1 count_part  : partial annulus counts, j-split (32 chunks), j processed
//                    in PAIRS via float2 -> v_pk_mul/add_f32 (IEEE-rn, bit-
//                    identical to scalar; fp contract OFF blocks pk_fma).
//                    Partials stored as ushort (count <= 128).
//   K2 rank_gather : sums ushort partials as packed pairs-in-int (sums <=4096,
//                    no cross-half carry) -> LDS keys; ranks 64 owned points;
//                    writes xyz + 64 features.
// key = cnt<<12 | (4095-i): one int compare == lax.top_k (count desc, index
// asc) order; ranks are a permutation so each output slot written once.
// grid.sync() measured ~45us/sync on gfx950 (round 4) -- kernel boundary is
// the cheap global barrier; do NOT re-fuse.

#pragma clang fp contract(off)

#define BN 4
#define NPTS 4096
#define ND 64
#define KSEL 2048
#define R2 0.0025f   // RADIUS^2
#define M2 0.0004f   // MIN_RADIUS^2

#define IPT 4         // i-points per thread
#define ITILES 4      // NPTS / (256*IPT)
#define JC 32         // j-chunks
#define JCH 128       // NPTS / JC
#define JP (JCH / 2)  // j-pairs per chunk

typedef float f32x2 __attribute__((ext_vector_type(2)));

// K1: grid = BN*ITILES*JC = 512 blocks (2 blocks/CU).
__global__ __launch_bounds__(256) void count_part_kernel(
        const float* __restrict__ xyz, unsigned short* __restrict__ part) {
    __shared__ float4 sA[JP];   // (x0, x1, y0, y1)
    __shared__ float4 sB[JP];   // (z0, z1, sq0, sq1)
    const int jc = blockIdx.x & (JC - 1);
    const int it = (blockIdx.x >> 5) & (ITILES - 1);
    const int b  = blockIdx.x >> 7;
    const float* base = xyz + (size_t)b * 3 * NPTS;

    if (threadIdx.x < JP) {
        int j0 = jc * JCH + 2 * threadIdx.x;
        float2 xv = *(const float2*)(base + j0);
        float2 yv = *(const float2*)(base + NPTS + j0);
        float2 zv = *(const float2*)(base + 2 * NPTS + j0);
        // sq = (x*x + y*y) + z*z, no FMA contraction (bit-match numpy)
        float sq0 = __fadd_rn(__fadd_rn(__fmul_rn(xv.x, xv.x),
                                        __fmul_rn(yv.x, yv.x)),
                              __fmul_rn(zv.x, zv.x));
        float sq1 = __fadd_rn(__fadd_rn(__fmul_rn(xv.y, xv.y),
                                        __fmul_rn(yv.y, yv.y)),
                              __fmul_rn(zv.y, zv.y));
        sA[threadIdx.x] = make_float4(xv.x, xv.y, yv.x, yv.y);
        sB[threadIdx.x] = make_float4(zv.x, zv.y, sq0, sq1);
    }
    const int ibase = it * 1024 + threadIdx.x;
    f32x2 mx[IPT], my[IPT], mz[IPT], ms[IPT];
    #pragma unroll
    for (int k = 0; k < IPT; ++k) {
        int i = ibase + k * 256;
        float x = base[i], y = base[NPTS + i], z = base[2 * NPTS + i];
        float sq = __fadd_rn(__fadd_rn(__fmul_rn(x, x), __fmul_rn(y, y)),
                             __fmul_rn(z, z));
        mx[k] = (f32x2){x, x};  my[k] = (f32x2){y, y};
        mz[k] = (f32x2){z, z};  ms[k] = (f32x2){sq, sq};
    }
    __syncthreads();

    int cnt[IPT] = {0, 0, 0, 0};
    const f32x2 two2 = {2.0f, 2.0f};
    #pragma unroll 2
    for (int jp = 0; jp < JP; ++jp) {
        float4 A = sA[jp], B = sB[jp];
        f32x2 px = {A.x, A.y}, py = {A.z, A.w};
        f32x2 pz = {B.x, B.y}, pw = {B.z, B.w};
        #pragma unroll
        for (int k = 0; k < IPT; ++k) {
            // dot = (x*x' + y*y') + z*z'; d2 = (sq_i + sq_j) - 2*dot
            // (packed rn ops are lane-wise identical to the scalar chain)
            f32x2 t0  = mx[k] * px;
            f32x2 t1  = my[k] * py;
            f32x2 t2  = mz[k] * pz;
            f32x2 dot = (t0 + t1) + t2;
            f32x2 d2  = (ms[k] + pw) - two2 * dot;
            cnt[k] += (d2.x < R2 && d2.x > M2) ? 1 : 0;
            cnt[k] += (d2.y < R2 && d2.y > M2) ? 1 : 0;
        }
    }
    unsigned short* pp = part + (size_t)((b * ITILES + it) * JC + jc) * 1024;
    #pragma unroll
    for (int k = 0; k < IPT; ++k)
        pp[threadIdx.x + k * 256] = (unsigned short)cnt[k];
}

// K2: grid = BN*64 = 256 blocks; block owns 64 consecutive i of batch b.
__global__ __launch_bounds__(256) void rank_gather_kernel(
        const float* __restrict__ xyz, const float* __restrict__ points,
        const unsigned short* __restrict__ part, float* __restrict__ out) {
    __shared__ alignas(16) int skey[NPTS];   // 16 KB
    __shared__ int spr[4][64];
    __shared__ int srank[64];
    const int b     = blockIdx.x >> 6;
    const int tbase = (blockIdx.x & 63) * 64;
    const int tid   = threadIdx.x;

    // ---- phase A: sum ushort partials for ALL 4096 points -> LDS keys.
    // Two point-counts packed per int; per-point sums <= 4096 so the low
    // half never carries into the high half -> plain int adds are exact.
    {
        const unsigned short* pbase = part + (size_t)b * ITILES * JC * 1024;
        #pragma unroll
        for (int gg = 0; gg < 2; ++gg) {
            const int g    = tid + gg * 256;   // int4 group of 8 points
            const int it   = g >> 7;           // 128 groups per itile
            const int loc8 = (g & 127) * 8;
            const int4* pp =
                (const int4*)(pbase + (size_t)it * JC * 1024 + loc8);
            int4 s = make_int4(0, 0, 0, 0);
            #pragma unroll 8
            for (int jc = 0; jc < JC; ++jc) {  // 1024 ushort = 128 int4 stride
                int4 v = pp[jc * 128];
                s.x += v.x; s.y += v.y; s.z += v.z; s.w += v.w;
            }
            const int i0 = it * 1024 + loc8;
            int4 ka, kb;
            ka.x = ((s.x & 0xFFFF) << 12)          | (NPTS - 1 - (i0 + 0));
            ka.y = (((unsigned)s.x >> 16) << 12)   | (NPTS - 1 - (i0 + 1));
            ka.z = ((s.y & 0xFFFF) << 12)          | (NPTS - 1 - (i0 + 2));
            ka.w = (((unsigned)s.y >> 16) << 12)   | (NPTS - 1 - (i0 + 3));
            kb.x = ((s.z & 0xFFFF) << 12)          | (NPTS - 1 - (i0 + 4));
            kb.y = (((unsigned)s.z >> 16) << 12)   | (NPTS - 1 - (i0 + 5));
            kb.z = ((s.w & 0xFFFF) << 12)          | (NPTS - 1 - (i0 + 6));
            kb.w = (((unsigned)s.w >> 16) << 12)   | (NPTS - 1 - (i0 + 7));
            ((int4*)skey)[g * 2]     = ka;
            ((int4*)skey)[g * 2 + 1] = kb;
        }
    }
    __syncthreads();

    // ---- phase B: rank own 64 points (wave-broadcast b128 reads, free)
    {
        const int pi = tid & 63;
        const int q  = tid >> 6;                  // 4 j-slices per point
        const int ki = skey[tbase + pi];
        const int4* sk4 = (const int4*)skey;
        int r = 0;
        #pragma unroll 8
        for (int jj = q * 256; jj < q * 256 + 256; ++jj) {
            int4 v = sk4[jj];
            r += (v.x > ki) ? 1 : 0;
            r += (v.y > ki) ? 1 : 0;
            r += (v.z > ki) ? 1 : 0;
            r += (v.w > ki) ? 1 : 0;
        }
        spr[q][pi] = r;
    }
    __syncthreads();

    if (tid < 64) {
        const int rank = spr[0][tid] + spr[1][tid] + spr[2][tid] + spr[3][tid];
        srank[tid] = rank;
        const int i = tbase + tid;
        if (rank < KSEL) {
            const float* xb = xyz + (size_t)b * 3 * NPTS;
            float* o = out + ((size_t)b * KSEL + rank) * 3;
            o[0] = xb[i]; o[1] = xb[NPTS + i]; o[2] = xb[2 * NPTS + i];
        }
    }
    __syncthreads();

    // ---- phase C: features; wave q covers c = q,q+4,...; lane = point
    {
        const int ii   = tid & 63;
        const int q    = tid >> 6;
        const int rank = srank[ii];
        float* ofeat = out + (size_t)BN * KSEL * 3;
        #pragma unroll
        for (int r16 = 0; r16 < 16; ++r16) {
            const int c = q + 4 * r16;
            float v = points[((size_t)b * ND + c) * NPTS + tbase + ii];
            if (rank < KSEL) ofeat[((size_t)b * KSEL + rank) * ND + c] = v;
        }
    }
}

extern "C" void kernel_launch(void* const* d_in, const int* in_sizes, int n_in,
                              void* d_out, int out_size, void* d_ws, size_t ws_size,
                              hipStream_t stream) {
    const float* xyz    = (const float*)d_in[0];   // [B, 3, N, 1]
    const float* points = (const float*)d_in[1];   // [B, D, N, 1]
    float* out = (float*)d_out;
    unsigned short* part = (unsigned short*)d_ws;  // 1 MB ushort partials

    count_part_kernel<<<BN * ITILES * JC, 256, 0, stream>>>(xyz, part);
    rank_gather_kernel<<<BN * 64, 256, 0, stream>>>(xyz, points, part, out);
}

// Round 7
// 85.337 us; speedup vs baseline: 2.0925x; 1.0477x over previous
//
#include <hip/hip_runtime.h>

// PoolObj: ball-query (annulus) neighbor-count downsampling + gather.
// B=4, N=4096, D=64, K=2048. Out = concat(new_xyz [B,K,3], new_points [B,K,D]).
//
// Fixed harness overhead (268MB ws 0xAA fill @ ~80% HBM peak = 40.5us, plus
// out poison / input restores / replay gaps) ~= 75us of the measured total;
// our kernels are ~14us of it.
//   K1 count_part  : partial annulus counts, j-split (32 chunks), j in PAIRS
//                    via float2 -> v_pk_mul/add_f32 (IEEE-rn, bit-identical;
//                    fp contract OFF). Annulus test done as ONE unsigned
//                    integer range-check on the float bits (exact: IEEE
//                    ordering == int ordering for positive floats, negatives
//                    map out of range). Partials stored as ushort (<=128).
//   K2 rank_gather : sums ushort partials as packed pairs-in-int (sums <=4096,
//                    no cross-half carry) -> LDS keys; ranks 64 owned points;
//                    writes xyz; features go through an LDS transpose tile so
//                    global writes are contiguous float4 runs per point.
// key = cnt<<12 | (4095-i): one int compare == lax.top_k (count desc, index
// asc) order; ranks are a permutation so each output slot written once.
// grid.sync() measured ~45us/sync on gfx950 (round 4) -- kernel boundary is
// the cheap global barrier; do NOT re-fuse.

#pragma clang fp contract(off)

#define BN 4
#define NPTS 4096
#define ND 64
#define KSEL 2048
#define R2 0.0025f   // RADIUS^2
#define M2 0.0004f   // MIN_RADIUS^2

#define IPT 4         // i-points per thread
#define ITILES 4      // NPTS / (256*IPT)
#define JC 32         // j-chunks
#define JCH 128       // NPTS / JC
#define JP (JCH / 2)  // j-pairs per chunk

typedef float f32x2 __attribute__((ext_vector_type(2)));

// K1: grid = BN*ITILES*JC = 512 blocks (2 blocks/CU).
__global__ __launch_bounds__(256) void count_part_kernel(
        const float* __restrict__ xyz, unsigned short* __restrict__ part) {
    __shared__ float4 sA[JP];   // (x0, x1, y0, y1)
    __shared__ float4 sB[JP];   // (z0, z1, sq0, sq1)
    const int jc = blockIdx.x & (JC - 1);
    const int it = (blockIdx.x >> 5) & (ITILES - 1);
    const int b  = blockIdx.x >> 7;
    const float* base = xyz + (size_t)b * 3 * NPTS;

    if (threadIdx.x < JP) {
        int j0 = jc * JCH + 2 * threadIdx.x;
        float2 xv = *(const float2*)(base + j0);
        float2 yv = *(const float2*)(base + NPTS + j0);
        float2 zv = *(const float2*)(base + 2 * NPTS + j0);
        // sq = (x*x + y*y) + z*z, no FMA contraction (bit-match numpy)
        float sq0 = __fadd_rn(__fadd_rn(__fmul_rn(xv.x, xv.x),
                                        __fmul_rn(yv.x, yv.x)),
                              __fmul_rn(zv.x, zv.x));
        float sq1 = __fadd_rn(__fadd_rn(__fmul_rn(xv.y, xv.y),
                                        __fmul_rn(yv.y, yv.y)),
                              __fmul_rn(zv.y, zv.y));
        sA[threadIdx.x] = make_float4(xv.x, xv.y, yv.x, yv.y);
        sB[threadIdx.x] = make_float4(zv.x, zv.y, sq0, sq1);
    }
    const int ibase = it * 1024 + threadIdx.x;
    f32x2 mx[IPT], my[IPT], mz[IPT], ms[IPT];
    #pragma unroll
    for (int k = 0; k < IPT; ++k) {
        int i = ibase + k * 256;
        float x = base[i], y = base[NPTS + i], z = base[2 * NPTS + i];
        float sq = __fadd_rn(__fadd_rn(__fmul_rn(x, x), __fmul_rn(y, y)),
                             __fmul_rn(z, z));
        mx[k] = (f32x2){x, x};  my[k] = (f32x2){y, y};
        mz[k] = (f32x2){z, z};  ms[k] = (f32x2){sq, sq};
    }
    __syncthreads();

    // Annulus test as one unsigned range check on the float bits:
    //   M2 < d2 < R2  <=>  (unsigned)(bits(d2) - bits(M2) - 1) < RANGE.
    // Exact: positive-float IEEE order == int order; d2<=M2 or negative or
    // >=R2 all fall outside [0, RANGE). No rounding behavior is changed.
    const int      m2i1  = __float_as_int(M2) + 1;
    const unsigned range = (unsigned)(__float_as_int(R2) - __float_as_int(M2)) - 1u;

    int cnt[IPT] = {0, 0, 0, 0};
    const f32x2 two2 = {2.0f, 2.0f};
    #pragma unroll 2
    for (int jp = 0; jp < JP; ++jp) {
        float4 A = sA[jp], B = sB[jp];
        f32x2 px = {A.x, A.y}, py = {A.z, A.w};
        f32x2 pz = {B.x, B.y}, pw = {B.z, B.w};
        #pragma unroll
        for (int k = 0; k < IPT; ++k) {
            // dot = (x*x' + y*y') + z*z'; d2 = (sq_i + sq_j) - 2*dot
            // (packed rn ops are lane-wise identical to the scalar chain)
            f32x2 t0  = mx[k] * px;
            f32x2 t1  = my[k] * py;
            f32x2 t2  = mz[k] * pz;
            f32x2 dot = (t0 + t1) + t2;
            f32x2 d2  = (ms[k] + pw) - two2 * dot;
            cnt[k] += ((unsigned)(__float_as_int(d2.x) - m2i1) < range) ? 1 : 0;
            cnt[k] += ((unsigned)(__float_as_int(d2.y) - m2i1) < range) ? 1 : 0;
        }
    }
    unsigned short* pp = part + (size_t)((b * ITILES + it) * JC + jc) * 1024;
    #pragma unroll
    for (int k = 0; k < IPT; ++k)
        pp[threadIdx.x + k * 256] = (unsigned short)cnt[k];
}

// K2: grid = BN*64 = 256 blocks; block owns 64 consecutive i of batch b.
__global__ __launch_bounds__(256) void rank_gather_kernel(
        const float* __restrict__ xyz, const float* __restrict__ points,
        const unsigned short* __restrict__ part, float* __restrict__ out) {
    __shared__ union {
        alignas(16) int skey[NPTS];     // phases A/B: 16 KB keys
        float sfeat[ND][68];            // phase C: transpose tile (pad 68:
    } sh;                               //   68%32==4 -> 2-way LDS = free)
    __shared__ int spr[4][64];
    __shared__ int srank[64];
    const int b     = blockIdx.x >> 6;
    const int tbase = (blockIdx.x & 63) * 64;
    const int tid   = threadIdx.x;

    // ---- phase A: sum ushort partials for ALL 4096 points -> LDS keys.
    // Two point-counts packed per int; per-point sums <= 4096 so the low
    // half never carries into the high half -> plain int adds are exact.
    {
        const unsigned short* pbase = part + (size_t)b * ITILES * JC * 1024;
        #pragma unroll
        for (int gg = 0; gg < 2; ++gg) {
            const int g    = tid + gg * 256;   // int4 group of 8 points
            const int it   = g >> 7;           // 128 groups per itile
            const int loc8 = (g & 127) * 8;
            const int4* pp =
                (const int4*)(pbase + (size_t)it * JC * 1024 + loc8);
            int4 s = make_int4(0, 0, 0, 0);
            #pragma unroll 8
            for (int jc = 0; jc < JC; ++jc) {  // 1024 ushort = 128 int4 stride
                int4 v = pp[jc * 128];
                s.x += v.x; s.y += v.y; s.z += v.z; s.w += v.w;
            }
            const int i0 = it * 1024 + loc8;
            int4 ka, kb;
            ka.x = ((s.x & 0xFFFF) << 12)          | (NPTS - 1 - (i0 + 0));
            ka.y = (((unsigned)s.x >> 16) << 12)   | (NPTS - 1 - (i0 + 1));
            ka.z = ((s.y & 0xFFFF) << 12)          | (NPTS - 1 - (i0 + 2));
            ka.w = (((unsigned)s.y >> 16) << 12)   | (NPTS - 1 - (i0 + 3));
            kb.x = ((s.z & 0xFFFF) << 12)          | (NPTS - 1 - (i0 + 4));
            kb.y = (((unsigned)s.z >> 16) << 12)   | (NPTS - 1 - (i0 + 5));
            kb.z = ((s.w & 0xFFFF) << 12)          | (NPTS - 1 - (i0 + 6));
            kb.w = (((unsigned)s.w >> 16) << 12)   | (NPTS - 1 - (i0 + 7));
            ((int4*)sh.skey)[g * 2]     = ka;
            ((int4*)sh.skey)[g * 2 + 1] = kb;
        }
    }
    __syncthreads();

    // ---- phase B: rank own 64 points (wave-broadcast b128 reads, free)
    {
        const int pi = tid & 63;
        const int q  = tid >> 6;                  // 4 j-slices per point
        const int ki = sh.skey[tbase + pi];
        const int4* sk4 = (const int4*)sh.skey;
        int r = 0;
        #pragma unroll 8
        for (int jj = q * 256; jj < q * 256 + 256; ++jj) {
            int4 v = sk4[jj];
            r += (v.x > ki) ? 1 : 0;
            r += (v.y > ki) ? 1 : 0;
            r += (v.z > ki) ? 1 : 0;
            r += (v.w > ki) ? 1 : 0;
        }
        spr[q][pi] = r;
    }
    __syncthreads();

    if (tid < 64) {
        const int rank = spr[0][tid] + spr[1][tid] + spr[2][tid] + spr[3][tid];
        srank[tid] = rank;
        const int i = tbase + tid;
        if (rank < KSEL) {
            const float* xb = xyz + (size_t)b * 3 * NPTS;
            float* o = out + ((size_t)b * KSEL + rank) * 3;
            o[0] = xb[i]; o[1] = xb[NPTS + i]; o[2] = xb[2 * NPTS + i];
        }
    }
    __syncthreads();   // also: skey dead from here, sfeat may overwrite

    // ---- phase C: features via LDS transpose.
    // Load: lane = point (coalesced 256B global reads), LDS 2-way free.
    {
        const int ii = tid & 63;
        const int q  = tid >> 6;
        #pragma unroll
        for (int r16 = 0; r16 < 16; ++r16) {
            const int c = q + 4 * r16;
            sh.sfeat[c][ii] = points[((size_t)b * ND + c) * NPTS + tbase + ii];
        }
    }
    __syncthreads();

    // Write: 4 threads per point, contiguous float4 runs per output row
    // (16 x 64B segments per store inst instead of 64 x 4B scatters).
    {
        const int pt = tid >> 2;        // 0..63
        const int c4 = tid & 3;
        const int rank = srank[pt];
        if (rank < KSEL) {
            float* orow = out + (size_t)BN * KSEL * 3 +
                          ((size_t)b * KSEL + rank) * ND;
            #pragma unroll
            for (int u4 = 0; u4 < 4; ++u4) {
                const int c0 = u4 * 16 + c4 * 4;
                float4 v = make_float4(sh.sfeat[c0 + 0][pt],
                                       sh.sfeat[c0 + 1][pt],
                                       sh.sfeat[c0 + 2][pt],
                                       sh.sfeat[c0 + 3][pt]);
                *(float4*)(orow + c0) = v;
            }
        }
    }
}

extern "C" void kernel_launch(void* const* d_in, const int* in_sizes, int n_in,
                              void* d_out, int out_size, void* d_ws, size_t ws_size,
                              hipStream_t stream) {
    const float* xyz    = (const float*)d_in[0];   // [B, 3, N, 1]
    const float* points = (const float*)d_in[1];   // [B, D, N, 1]
    float* out = (float*)d_out;
    unsigned short* part = (unsigned short*)d_ws;  // 1 MB ushort partials

    count_part_kernel<<<BN * ITILES * JC, 256, 0, stream>>>(xyz, part);
    rank_gather_kernel<<<BN * 64, 256, 0, stream>>>(xyz, points, part, out);
}